// Round 5
// baseline (136.180 us; speedup 1.0000x reference)
//
#include <hip/hip_runtime.h>
#include <stdint.h>

// Problem constants (fixed by the reference)
#define B_      16
#define N_      2048
#define M_      8192
#define ROWS    (B_ * N_)        // 32768
#define D_      8                // 4*2 flattened

// Single-kernel tiling: block = 256 threads = 4 waves; each wave owns 8 rows
// (replicated across its 64 lanes' registers); lanes scan disjoint anchors.
#define BLK     256
#define RPW     8                // rows per wave (all in each lane's regs)
#define WPB     4                // waves per block
#define RPB     (RPW * WPB)      // 32 rows per block
#define NBLK    (ROWS / RPB)     // 1024 blocks -> 4 blocks/CU
#define CHUNK   512              // anchors staged per LDS chunk
#define NCHUNK  (M_ / CHUNK)     // 16
#define STEPS   (CHUNK / 64)     // 8 lane-strided steps per chunk

// LDS: separate float4 arrays => 16B-aligned, lane-contiguous ds_read_b128
// (the measured-optimal pattern; a [512][9] AoS layout would break b128
// alignment, a [512][12] layout would 8-way bank-conflict).
// 2 buffers x (8KB + 8KB + 2KB) = 36 KB; x4 blocks/CU = 144 KB <= 160 KB.
__global__ __launch_bounds__(BLK, 4) void colddiff_kernel(
    const float* __restrict__ x,        // [ROWS][8]
    const float* __restrict__ anchors,  // [M_][8]
    const float* __restrict__ sa_tab,   // [1000]
    const float* __restrict__ sb_tab,   // [1000]
    const int*   __restrict__ t,        // [B_]
    float* __restrict__ out)            // [ROWS][8]
{
    __shared__ float4 sA0[2][CHUNK];    // negated anchor floats 0..3
    __shared__ float4 sA1[2][CHUNK];    // negated anchor floats 4..7
    __shared__ float  sH [2][CHUNK];    // 0.5*||a||^2

    const int tid  = threadIdx.x;
    const int lane = tid & 63;
    const int wave = tid >> 6;
    const int rowbase = blockIdx.x * RPB + wave * RPW;

    // Stage one chunk: each thread handles 2 anchors.
    auto stage = [&](int c, int b) {
        #pragma unroll
        for (int i = 0; i < CHUNK / BLK; ++i) {         // 2 iters
            const int slot = tid + i * BLK;
            const int g = c * CHUNK + slot;
            const float4* pa = (const float4*)(anchors + (size_t)g * D_);
            const float4 a0 = pa[0], a1 = pa[1];
            float nr = a0.x * a0.x;
            nr = fmaf(a0.y, a0.y, nr);
            nr = fmaf(a0.z, a0.z, nr);
            nr = fmaf(a0.w, a0.w, nr);
            nr = fmaf(a1.x, a1.x, nr);
            nr = fmaf(a1.y, a1.y, nr);
            nr = fmaf(a1.z, a1.z, nr);
            nr = fmaf(a1.w, a1.w, nr);
            sA0[b][slot] = (float4){-a0.x, -a0.y, -a0.z, -a0.w};
            sA1[b][slot] = (float4){-a1.x, -a1.y, -a1.z, -a1.w};
            sH [b][slot] = 0.5f * nr;
        }
    };

    // This wave's 8 rows into registers (same addresses across lanes -> L1)
    float X[RPW][D_];
    #pragma unroll
    for (int r = 0; r < RPW; ++r) {
        const float4* px = (const float4*)(x + (size_t)(rowbase + r) * D_);
        const float4 lo = px[0], hi = px[1];
        X[r][0] = lo.x; X[r][1] = lo.y; X[r][2] = lo.z; X[r][3] = lo.w;
        X[r][4] = hi.x; X[r][5] = hi.y; X[r][6] = hi.z; X[r][7] = hi.w;
    }

    float best[RPW];
    int   bidx[RPW];
    #pragma unroll
    for (int r = 0; r < RPW; ++r) { best[r] = 3.4e38f; bidx[r] = 0; }

    stage(0, 0);

    // Double-buffered chunk loop: one barrier per chunk; staging of chunk c+1
    // overlaps compute of chunk c.
    for (int c = 0; c < NCHUNK; ++c) {
        __syncthreads();
        if (c + 1 < NCHUNK) stage(c + 1, (c + 1) & 1);
        const int b = c & 1;
        #pragma unroll 2
        for (int k = 0; k < STEPS; ++k) {
            const int slot = k * 64 + lane;             // lane-contiguous b128
            const float4 a0 = sA0[b][slot];
            const float4 a1 = sA1[b][slot];
            const float  hn = sH [b][slot];
            const int    j  = c * CHUNK + slot;
            #pragma unroll
            for (int r = 0; r < RPW; ++r) {
                float s = fmaf(X[r][0], a0.x, hn);      // hn + sum x*(-a)
                s = fmaf(X[r][1], a0.y, s);
                s = fmaf(X[r][2], a0.z, s);
                s = fmaf(X[r][3], a0.w, s);
                s = fmaf(X[r][4], a1.x, s);
                s = fmaf(X[r][5], a1.y, s);
                s = fmaf(X[r][6], a1.z, s);
                s = fmaf(X[r][7], a1.w, s);
                // strict '<' + ascending j => lowest index kept on ties
                const bool cc = s < best[r];
                best[r] = cc ? s : best[r];
                bidx[r] = cc ? j : bidx[r];
            }
        }
    }

    // Per-wave lexicographic (score, idx) butterfly min: every lane ends with
    // the global winner per row; idx tie-break == jnp.argmin first-occurrence.
    #pragma unroll
    for (int r = 0; r < RPW; ++r) {
        #pragma unroll
        for (int m = 1; m < 64; m <<= 1) {
            const float ov = __shfl_xor(best[r], m);
            const int   oj = __shfl_xor(bidx[r], m);
            const bool take = (ov < best[r]) || (ov == best[r] && oj < bidx[r]);
            best[r] = take ? ov : best[r];
            bidx[r] = take ? oj : bidx[r];
        }
    }

    // Lanes 0..7 each emit one row (fused q_sample epilogue).
    if (lane < RPW) {
        int selj = bidx[0];
        #pragma unroll
        for (int r = 1; r < RPW; ++r) selj = (lane == r) ? bidx[r] : selj;

        const int row = rowbase + lane;
        const int tb  = t[row >> 11];                   // row / N_
        const float sa = sa_tab[tb];
        const float sb = sb_tab[tb];

        const float4* px = (const float4*)(x + (size_t)row * D_);
        const float4* pa = (const float4*)(anchors + (size_t)selj * D_);
        const float4 x0 = px[0], x1 = px[1];
        const float4 a0 = pa[0], a1 = pa[1];

        float4 o0, o1;
        o0.x = fmaf(sa, x0.x, sb * a0.x);
        o0.y = fmaf(sa, x0.y, sb * a0.y);
        o0.z = fmaf(sa, x0.z, sb * a0.z);
        o0.w = fmaf(sa, x0.w, sb * a0.w);
        o1.x = fmaf(sa, x1.x, sb * a1.x);
        o1.y = fmaf(sa, x1.y, sb * a1.y);
        o1.z = fmaf(sa, x1.z, sb * a1.z);
        o1.w = fmaf(sa, x1.w, sb * a1.w);

        float4* po = (float4*)(out + (size_t)row * D_);
        po[0] = o0;
        po[1] = o1;
    }
}

extern "C" void kernel_launch(void* const* d_in, const int* in_sizes, int n_in,
                              void* d_out, int out_size, void* d_ws, size_t ws_size,
                              hipStream_t stream) {
    const float* x       = (const float*)d_in[0];  // x_start [16,2048,4,2]
    const float* anchors = (const float*)d_in[1];  // anchors [8192,4,2]
    const float* sa_tab  = (const float*)d_in[2];  // sqrt_alphas_cumprod [1000]
    const float* sb_tab  = (const float*)d_in[3];  // sqrt_one_minus_alphas_cumprod [1000]
    const int*   t       = (const int*)d_in[4];    // t [16]
    float* out = (float*)d_out;

    colddiff_kernel<<<NBLK, BLK, 0, stream>>>(x, anchors, sa_tab, sb_tab, t, out);
}

// Round 6
// 134.113 us; speedup vs baseline: 1.0154x; 1.0154x over previous
//
#include <hip/hip_runtime.h>
#include <stdint.h>

// Problem constants (fixed by the reference)
#define B_      16
#define N_      2048
#define M_      8192
#define ROWS    (B_ * N_)        // 32768
#define D_      8                // 4*2 flattened

// Single-kernel tiling: block = 256 threads = 4 waves; each wave owns 8 rows
// (replicated across its 64 lanes' registers); lanes scan disjoint anchors.
#define BLK     256
#define RPW     8                // rows per wave (in each lane's registers)
#define WPB     4                // waves per block
#define RPB     (RPW * WPB)      // 32 rows per block
#define NBLK    (ROWS / RPB)     // 1024 blocks -> 4 blocks/CU resident
#define CHUNK   512              // anchors staged per LDS chunk
#define NCHUNK  (M_ / CHUNK)     // 16
#define STEPS   (CHUNK / 64)     // 8 lane-strided steps per chunk
#define PFPT    (CHUNK / BLK)    // 2 anchors prefetched per thread

// LDS: single buffer, separate float4 arrays (16B-aligned lane-contiguous
// ds_read_b128, conflict-free). 8KB + 8KB + 2KB = 18KB -> 4 blocks/CU = 72KB.
// Pipeline per chunk: [barrier; regs->LDS; barrier; issue next prefetch;
// compute] — global-load drain overlaps a full chunk of compute.
__global__ __launch_bounds__(BLK, 4) void colddiff_kernel(
    const float* __restrict__ x,        // [ROWS][8]
    const float* __restrict__ anchors,  // [M_][8]
    const float* __restrict__ sa_tab,   // [1000]
    const float* __restrict__ sb_tab,   // [1000]
    const int*   __restrict__ t,        // [B_]
    float* __restrict__ out)            // [ROWS][8]
{
    __shared__ float4 sA0[CHUNK];       // anchor floats 0..3 (raw)
    __shared__ float4 sA1[CHUNK];       // anchor floats 4..7 (raw)
    __shared__ float  sH [CHUNK];       // 0.5*||a||^2

    const int tid  = threadIdx.x;
    const int lane = tid & 63;
    const int wave = tid >> 6;
    const int rowbase = blockIdx.x * RPB + wave * RPW;

    // My wave's 8 rows, NEGATED at load (fmaf(-x, a, .) == fmaf(x, -a, .) exactly).
    // 64 floats — must stay in arch VGPRs (total live ~110 <= 128 budget).
    float Xn[RPW][D_];
    #pragma unroll
    for (int r = 0; r < RPW; ++r) {
        const float4* px = (const float4*)(x + (size_t)(rowbase + r) * D_);
        const float4 lo = px[0], hi = px[1];
        Xn[r][0] = -lo.x; Xn[r][1] = -lo.y; Xn[r][2] = -lo.z; Xn[r][3] = -lo.w;
        Xn[r][4] = -hi.x; Xn[r][5] = -hi.y; Xn[r][6] = -hi.z; Xn[r][7] = -hi.w;
    }

    float best[RPW];
    int   bidx[RPW];
    #pragma unroll
    for (int r = 0; r < RPW; ++r) { best[r] = 3.4e38f; bidx[r] = 0; }

    // Prefetch chunk 0 into registers (4 float4 = 16 VGPRs)
    const float4* gA = (const float4*)anchors;
    float4 p0[PFPT], p1[PFPT];
    #pragma unroll
    for (int i = 0; i < PFPT; ++i) {
        const int slot = tid + i * BLK;
        p0[i] = gA[2 * slot];
        p1[i] = gA[2 * slot + 1];
    }

    for (int c = 0; c < NCHUNK; ++c) {
        __syncthreads();                 // LDS of chunk c-1 fully consumed
        // Write prefetched chunk c to LDS (+ half-norms from registers)
        #pragma unroll
        for (int i = 0; i < PFPT; ++i) {
            const int slot = tid + i * BLK;
            const float4 a0 = p0[i], a1 = p1[i];
            float nr = a0.x * a0.x;
            nr = fmaf(a0.y, a0.y, nr);
            nr = fmaf(a0.z, a0.z, nr);
            nr = fmaf(a0.w, a0.w, nr);
            nr = fmaf(a1.x, a1.x, nr);
            nr = fmaf(a1.y, a1.y, nr);
            nr = fmaf(a1.z, a1.z, nr);
            nr = fmaf(a1.w, a1.w, nr);
            sA0[slot] = a0;
            sA1[slot] = a1;
            sH [slot] = 0.5f * nr;
        }
        __syncthreads();
        // Issue next chunk's global loads; they drain during compute below
        if (c + 1 < NCHUNK) {
            #pragma unroll
            for (int i = 0; i < PFPT; ++i) {
                const int slot = (c + 1) * CHUNK + tid + i * BLK;
                p0[i] = gA[2 * slot];
                p1[i] = gA[2 * slot + 1];
            }
        }
        // Hot loop: per (slot, row) = 8 fmaf + cmp + 2 cndmask (11 instr)
        #pragma unroll 2
        for (int k = 0; k < STEPS; ++k) {
            const int slot = k * 64 + lane;          // lane-contiguous b128
            const float4 a0 = sA0[slot];
            const float4 a1 = sA1[slot];
            const float  hn = sH [slot];
            const int    j  = c * CHUNK + slot;
            #pragma unroll
            for (int r = 0; r < RPW; ++r) {
                float s = fmaf(Xn[r][0], a0.x, hn);  // hn - x.a
                s = fmaf(Xn[r][1], a0.y, s);
                s = fmaf(Xn[r][2], a0.z, s);
                s = fmaf(Xn[r][3], a0.w, s);
                s = fmaf(Xn[r][4], a1.x, s);
                s = fmaf(Xn[r][5], a1.y, s);
                s = fmaf(Xn[r][6], a1.z, s);
                s = fmaf(Xn[r][7], a1.w, s);
                // strict '<' + ascending j => lowest index kept on ties
                const bool cc = s < best[r];
                best[r] = cc ? s : best[r];
                bidx[r] = cc ? j : bidx[r];
            }
        }
    }

    // Per-wave lexicographic (score, idx) butterfly min; idx tie-break ==
    // jnp.argmin first-occurrence (lanes hold disjoint ascending j sets).
    #pragma unroll
    for (int r = 0; r < RPW; ++r) {
        #pragma unroll
        for (int m = 1; m < 64; m <<= 1) {
            const float ov = __shfl_xor(best[r], m);
            const int   oj = __shfl_xor(bidx[r], m);
            const bool take = (ov < best[r]) || (ov == best[r] && oj < bidx[r]);
            best[r] = take ? ov : best[r];
            bidx[r] = take ? oj : bidx[r];
        }
    }

    // Lanes 0..7 each emit one row (fused q_sample epilogue).
    if (lane < RPW) {
        int selj = bidx[0];
        #pragma unroll
        for (int r = 1; r < RPW; ++r) selj = (lane == r) ? bidx[r] : selj;

        const int row = rowbase + lane;
        const int tb  = t[row >> 11];               // row / N_
        const float sa = sa_tab[tb];
        const float sb = sb_tab[tb];

        const float4* px = (const float4*)(x + (size_t)row * D_);
        const float4* pa = (const float4*)(anchors + (size_t)selj * D_);
        const float4 x0 = px[0], x1 = px[1];
        const float4 a0 = pa[0], a1 = pa[1];

        float4 o0, o1;
        o0.x = fmaf(sa, x0.x, sb * a0.x);
        o0.y = fmaf(sa, x0.y, sb * a0.y);
        o0.z = fmaf(sa, x0.z, sb * a0.z);
        o0.w = fmaf(sa, x0.w, sb * a0.w);
        o1.x = fmaf(sa, x1.x, sb * a1.x);
        o1.y = fmaf(sa, x1.y, sb * a1.y);
        o1.z = fmaf(sa, x1.z, sb * a1.z);
        o1.w = fmaf(sa, x1.w, sb * a1.w);

        float4* po = (float4*)(out + (size_t)row * D_);
        po[0] = o0;
        po[1] = o1;
    }
}

extern "C" void kernel_launch(void* const* d_in, const int* in_sizes, int n_in,
                              void* d_out, int out_size, void* d_ws, size_t ws_size,
                              hipStream_t stream) {
    const float* x       = (const float*)d_in[0];  // x_start [16,2048,4,2]
    const float* anchors = (const float*)d_in[1];  // anchors [8192,4,2]
    const float* sa_tab  = (const float*)d_in[2];  // sqrt_alphas_cumprod [1000]
    const float* sb_tab  = (const float*)d_in[3];  // sqrt_one_minus_alphas_cumprod [1000]
    const int*   t       = (const int*)d_in[4];    // t [16]
    float* out = (float*)d_out;

    colddiff_kernel<<<NBLK, BLK, 0, stream>>>(x, anchors, sa_tab, sb_tab, t, out);
}

// Round 7
// 128.844 us; speedup vs baseline: 1.0569x; 1.0409x over previous
//
#include <hip/hip_runtime.h>
#include <stdint.h>

// Problem constants (fixed by the reference)
#define B_      16
#define N_      2048
#define M_      8192
#define ROWS    (B_ * N_)        // 32768
#define D_      8                // 4*2 flattened

// Single-kernel tiling: block = 256 threads = 4 waves; each wave owns 8 rows
// (wave-uniform -> held in SGPRs); lanes scan disjoint anchors.
#define BLK     256
#define RPW     8                // rows per wave (in SGPRs, uniform across lanes)
#define WPB     4                // waves per block
#define RPB     (RPW * WPB)      // 32 rows per block
#define NBLK    (ROWS / RPB)     // 1024 blocks -> 4 blocks/CU resident
#define CHUNK   512              // anchors staged per LDS chunk
#define NCHUNK  (M_ / CHUNK)     // 16
#define STEPS   (CHUNK / 64)     // 8 lane-strided steps per chunk
#define PFPT    (CHUNK / BLK)    // 2 anchors prefetched per thread

// Force a wave-uniform float into an SGPR (bit-exact: value identical on all lanes).
__device__ __forceinline__ float rfl(float v) {
    return __int_as_float(__builtin_amdgcn_readfirstlane(__float_as_int(v)));
}

// LDS: single buffer, separate float4 arrays (16B-aligned lane-contiguous
// ds_read_b128, conflict-free). 8KB + 8KB + 2KB = 18KB -> 4 blocks/CU = 72KB.
// Hot-loop fmaf shape: v_fma_f32 vdst, sgpr(X), vgpr(anchor), vgpr(acc) —
// one SGPR read per VALU instr is architecturally free.
__global__ __launch_bounds__(BLK, 4) void colddiff_kernel(
    const float* __restrict__ x,        // [ROWS][8]
    const float* __restrict__ anchors,  // [M_][8]
    const float* __restrict__ sa_tab,   // [1000]
    const float* __restrict__ sb_tab,   // [1000]
    const int*   __restrict__ t,        // [B_]
    float* __restrict__ out)            // [ROWS][8]
{
    __shared__ float4 sA0[CHUNK];       // anchor floats 0..3 (raw)
    __shared__ float4 sA1[CHUNK];       // anchor floats 4..7 (raw)
    __shared__ float  sH [CHUNK];       // 0.5*||a||^2

    const int tid  = threadIdx.x;
    const int lane = tid & 63;
    const int wave = tid >> 6;
    const int rowbase = blockIdx.x * RPB + wave * RPW;

    // My wave's 8 rows, NEGATED, into SGPRs (fmaf(-x,a,.) == fmaf(x,-a,.) exactly).
    // 64 wave-uniform scalars: zero VGPR cost in the hot loop.
    float Xs[RPW][D_];
    #pragma unroll
    for (int r = 0; r < RPW; ++r) {
        const float4* px = (const float4*)(x + (size_t)(rowbase + r) * D_);
        const float4 lo = px[0], hi = px[1];
        Xs[r][0] = rfl(-lo.x); Xs[r][1] = rfl(-lo.y);
        Xs[r][2] = rfl(-lo.z); Xs[r][3] = rfl(-lo.w);
        Xs[r][4] = rfl(-hi.x); Xs[r][5] = rfl(-hi.y);
        Xs[r][6] = rfl(-hi.z); Xs[r][7] = rfl(-hi.w);
    }

    float best[RPW];
    int   bidx[RPW];
    #pragma unroll
    for (int r = 0; r < RPW; ++r) { best[r] = 3.4e38f; bidx[r] = 0; }

    // Prefetch chunk 0 into registers (4 float4 = 16 VGPRs)
    const float4* gA = (const float4*)anchors;
    float4 p0[PFPT], p1[PFPT];
    #pragma unroll
    for (int i = 0; i < PFPT; ++i) {
        const int slot = tid + i * BLK;
        p0[i] = gA[2 * slot];
        p1[i] = gA[2 * slot + 1];
    }

    for (int c = 0; c < NCHUNK; ++c) {
        __syncthreads();                 // LDS of chunk c-1 fully consumed
        // Write prefetched chunk c to LDS (+ half-norms from registers)
        #pragma unroll
        for (int i = 0; i < PFPT; ++i) {
            const int slot = tid + i * BLK;
            const float4 a0 = p0[i], a1 = p1[i];
            float nr = a0.x * a0.x;
            nr = fmaf(a0.y, a0.y, nr);
            nr = fmaf(a0.z, a0.z, nr);
            nr = fmaf(a0.w, a0.w, nr);
            nr = fmaf(a1.x, a1.x, nr);
            nr = fmaf(a1.y, a1.y, nr);
            nr = fmaf(a1.z, a1.z, nr);
            nr = fmaf(a1.w, a1.w, nr);
            sA0[slot] = a0;
            sA1[slot] = a1;
            sH [slot] = 0.5f * nr;
        }
        __syncthreads();
        // Issue next chunk's global loads; they drain during compute below
        if (c + 1 < NCHUNK) {
            #pragma unroll
            for (int i = 0; i < PFPT; ++i) {
                const int slot = (c + 1) * CHUNK + tid + i * BLK;
                p0[i] = gA[2 * slot];
                p1[i] = gA[2 * slot + 1];
            }
        }
        // Hot loop: per (slot, row) = 8 fmaf + cmp + 2 cndmask (11 instr)
        #pragma unroll 2
        for (int k = 0; k < STEPS; ++k) {
            const int slot = k * 64 + lane;          // lane-contiguous b128
            const float4 a0 = sA0[slot];
            const float4 a1 = sA1[slot];
            const float  hn = sH [slot];
            const int    j  = c * CHUNK + slot;
            #pragma unroll
            for (int r = 0; r < RPW; ++r) {
                float s = fmaf(Xs[r][0], a0.x, hn);  // hn - x.a
                s = fmaf(Xs[r][1], a0.y, s);
                s = fmaf(Xs[r][2], a0.z, s);
                s = fmaf(Xs[r][3], a0.w, s);
                s = fmaf(Xs[r][4], a1.x, s);
                s = fmaf(Xs[r][5], a1.y, s);
                s = fmaf(Xs[r][6], a1.z, s);
                s = fmaf(Xs[r][7], a1.w, s);
                // strict '<' + ascending j => lowest index kept on ties
                const bool cc = s < best[r];
                best[r] = cc ? s : best[r];
                bidx[r] = cc ? j : bidx[r];
            }
        }
    }

    // Per-wave lexicographic (score, idx) butterfly min; idx tie-break ==
    // jnp.argmin first-occurrence (lanes hold disjoint ascending j sets).
    #pragma unroll
    for (int r = 0; r < RPW; ++r) {
        #pragma unroll
        for (int m = 1; m < 64; m <<= 1) {
            const float ov = __shfl_xor(best[r], m);
            const int   oj = __shfl_xor(bidx[r], m);
            const bool take = (ov < best[r]) || (ov == best[r] && oj < bidx[r]);
            best[r] = take ? ov : best[r];
            bidx[r] = take ? oj : bidx[r];
        }
    }

    // Lanes 0..7 each emit one row (fused q_sample epilogue).
    if (lane < RPW) {
        int selj = bidx[0];
        #pragma unroll
        for (int r = 1; r < RPW; ++r) selj = (lane == r) ? bidx[r] : selj;

        const int row = rowbase + lane;
        const int tb  = t[row >> 11];               // row / N_
        const float sa = sa_tab[tb];
        const float sb = sb_tab[tb];

        const float4* px = (const float4*)(x + (size_t)row * D_);
        const float4* pa = (const float4*)(anchors + (size_t)selj * D_);
        const float4 x0 = px[0], x1 = px[1];
        const float4 a0 = pa[0], a1 = pa[1];

        float4 o0, o1;
        o0.x = fmaf(sa, x0.x, sb * a0.x);
        o0.y = fmaf(sa, x0.y, sb * a0.y);
        o0.z = fmaf(sa, x0.z, sb * a0.z);
        o0.w = fmaf(sa, x0.w, sb * a0.w);
        o1.x = fmaf(sa, x1.x, sb * a1.x);
        o1.y = fmaf(sa, x1.y, sb * a1.y);
        o1.z = fmaf(sa, x1.z, sb * a1.z);
        o1.w = fmaf(sa, x1.w, sb * a1.w);

        float4* po = (float4*)(out + (size_t)row * D_);
        po[0] = o0;
        po[1] = o1;
    }
}

extern "C" void kernel_launch(void* const* d_in, const int* in_sizes, int n_in,
                              void* d_out, int out_size, void* d_ws, size_t ws_size,
                              hipStream_t stream) {
    const float* x       = (const float*)d_in[0];  // x_start [16,2048,4,2]
    const float* anchors = (const float*)d_in[1];  // anchors [8192,4,2]
    const float* sa_tab  = (const float*)d_in[2];  // sqrt_alphas_cumprod [1000]
    const float* sb_tab  = (const float*)d_in[3];  // sqrt_one_minus_alphas_cumprod [1000]
    const int*   t       = (const int*)d_in[4];    // t [16]
    float* out = (float*)d_out;

    colddiff_kernel<<<NBLK, BLK, 0, stream>>>(x, anchors, sa_tab, sb_tab, t, out);
}